// Round 3
// baseline (4884.773 us; speedup 1.0000x reference)
//
#include <hip/hip_runtime.h>
#include <hip/hip_bf16.h>

// LFQ argmax: scores = x @ cb^T, out[n] = argmax_c, plus constant loss 0.
// Output buffer: float32[16385] (reference outputs are int32 indices + f32 loss
// -> harness "else float*" rule). Inputs probed at runtime: packed bf16 vs f32.
#define NT 16384   // tokens
#define ND 128     // dim
#define NC 16384   // codes
#define TPB 64     // tokens per block
#define NWAVES 8   // waves per block (512 threads)

typedef __bf16 bf16x8 __attribute__((ext_vector_type(8)));
typedef float f32x4 __attribute__((ext_vector_type(4)));

// dtype probe: packed-bf16 words carry a bf16 exponent in bits[14:7] of the
// low half (normal data -> ~100% in [96,150]); fp32 words have uniform
// mantissa bits there (~21%).
__global__ void lfq_probe(const unsigned int* __restrict__ xw,
                          int* __restrict__ flag) {
    int t = threadIdx.x;  // 64 threads
    int cnt = 0;
    for (int i = t; i < 4096; i += 64) {
        unsigned e = (xw[i] >> 7) & 0xFFu;
        cnt += (e >= 96u && e <= 150u) ? 1 : 0;
    }
#pragma unroll
    for (int off = 32; off > 0; off >>= 1) cnt += __shfl_down(cnt, off, 64);
    if (t == 0) *flag = (cnt >= 2048) ? 1 : 0;  // 1 = packed bf16, 0 = fp32
}

__global__ __launch_bounds__(512) void lfq_argmax_kernel(
    const void* __restrict__ x_,
    const void* __restrict__ cb_,
    float* __restrict__ out,          // float32 indices (+ loss at [NT])
    int out_size,
    const int* __restrict__ flag_p)
{
    const int tid  = threadIdx.x;
    const int w    = tid >> 6;        // wave id / code-stripe id, 0..7
    const int lane = tid & 63;
    const int n    = lane & 15;
    const int quad = lane >> 4;
    const int t0   = blockIdx.x * TPB;

    __shared__ float s_sc[NWAVES][TPB];
    __shared__ int   s_ix[NWAVES][TPB];

    const int is_bf16 = *flag_p;   // wave-uniform

    if (is_bf16) {
        // ================= bf16 MFMA path =================
        const __hip_bfloat16* x  = (const __hip_bfloat16*)x_;
        const __hip_bfloat16* cb = (const __hip_bfloat16*)cb_;

        bf16x8 a[4][4];  // A[m=lane&15][k=quad*8+j], 4 token-tiles x 4 k-chunks
#pragma unroll
        for (int tt = 0; tt < 4; ++tt) {
            const __hip_bfloat16* xr = x + (size_t)(t0 + tt * 16 + n) * ND + quad * 8;
#pragma unroll
            for (int kk = 0; kk < 4; ++kk)
                a[tt][kk] = *(const bf16x8*)(xr + kk * 32);
        }

        float best[4][4];
        int   bidx[4][4];
#pragma unroll
        for (int tt = 0; tt < 4; ++tt)
#pragma unroll
            for (int r = 0; r < 4; ++r) { best[tt][r] = -__builtin_inff(); bidx[tt][r] = 1; }
        // bidx init=1 is a diagnostic canary: "all-NaN scores" -> absmax 16383,
        // distinguishable from "kernel never ran" -> 16384. Finite data always
        // overwrites it on the first compare (score > -inf).

        for (int c = w * 16; c < NC; c += NWAVES * 16) {
            const __hip_bfloat16* br = cb + (size_t)(c + n) * ND + quad * 8;
            bf16x8 b[4];
#pragma unroll
            for (int kk = 0; kk < 4; ++kk)
                b[kk] = *(const bf16x8*)(br + kk * 32);

            const int code = c + n;
#pragma unroll
            for (int tt = 0; tt < 4; ++tt) {
                f32x4 acc = {0.f, 0.f, 0.f, 0.f};
#pragma unroll
                for (int kk = 0; kk < 4; ++kk)
                    acc = __builtin_amdgcn_mfma_f32_16x16x32_bf16(a[tt][kk], b[kk], acc, 0, 0, 0);
#pragma unroll
                for (int r = 0; r < 4; ++r)
                    if (acc[r] > best[tt][r]) { best[tt][r] = acc[r]; bidx[tt][r] = code; }
            }
        }

        // reduce across the 16 code-lanes per token row
#pragma unroll
        for (int tt = 0; tt < 4; ++tt)
#pragma unroll
            for (int r = 0; r < 4; ++r)
#pragma unroll
                for (int off = 1; off < 16; off <<= 1) {
                    float os = __shfl_xor(best[tt][r], off, 64);
                    int   oi = __shfl_xor(bidx[tt][r], off, 64);
                    if (os > best[tt][r] || (os == best[tt][r] && oi < bidx[tt][r])) {
                        best[tt][r] = os; bidx[tt][r] = oi;
                    }
                }

        if (n == 0) {
#pragma unroll
            for (int tt = 0; tt < 4; ++tt)
#pragma unroll
                for (int r = 0; r < 4; ++r) {
                    int slot = tt * 16 + quad * 4 + r;
                    s_sc[w][slot] = best[tt][r];
                    s_ix[w][slot] = bidx[tt][r];
                }
        }
    } else {
        // ================= exact fp32 VALU path =================
        const float* xf = (const float*)x_;
        const float* cf = (const float*)cb_;
        const int tok = tid & 63;     // token within block (one per lane)
        float4 xr[32];
        const float4* xrow = (const float4*)(xf + (size_t)(t0 + tok) * ND);
#pragma unroll
        for (int i = 0; i < 32; ++i) xr[i] = xrow[i];

        float bs = -__builtin_inff();
        int   bi = 1;                 // canary, see above
        const int c_begin = w * (NC / NWAVES);
        for (int c = c_begin; c < c_begin + NC / NWAVES; ++c) {
            const float4* crow = (const float4*)(cf + (size_t)c * ND);
            float a0 = 0.f, a1 = 0.f, a2 = 0.f, a3 = 0.f;
#pragma unroll
            for (int i = 0; i < 32; i += 4) {
                float4 v0 = crow[i + 0], v1 = crow[i + 1];
                float4 v2 = crow[i + 2], v3 = crow[i + 3];
                a0 += xr[i + 0].x * v0.x + xr[i + 0].y * v0.y + xr[i + 0].z * v0.z + xr[i + 0].w * v0.w;
                a1 += xr[i + 1].x * v1.x + xr[i + 1].y * v1.y + xr[i + 1].z * v1.z + xr[i + 1].w * v1.w;
                a2 += xr[i + 2].x * v2.x + xr[i + 2].y * v2.y + xr[i + 2].z * v2.z + xr[i + 2].w * v2.w;
                a3 += xr[i + 3].x * v3.x + xr[i + 3].y * v3.y + xr[i + 3].z * v3.z + xr[i + 3].w * v3.w;
            }
            float s = (a0 + a1) + (a2 + a3);
            if (s > bs) { bs = s; bi = c; }  // strict >, ascending c => first max
        }
        s_sc[w][tok] = bs;
        s_ix[w][tok] = bi;
    }

    __syncthreads();

    // combine the 8 disjoint code stripes per token; min-index tie-break
    if (tid < TPB) {
        float bs = s_sc[0][tid];
        int   bi = s_ix[0][tid];
#pragma unroll
        for (int ww = 1; ww < NWAVES; ++ww) {
            float s2 = s_sc[ww][tid];
            int   i2 = s_ix[ww][tid];
            if (s2 > bs || (s2 == bs && i2 < bi)) { bs = s2; bi = i2; }
        }
        out[t0 + tid] = (float)bi;   // float32 write — the round-3 fix
    }

    if (blockIdx.x == 0 && tid == 0 && out_size > NT)
        out[NT] = 0.0f;              // constant loss

}

extern "C" void kernel_launch(void* const* d_in, const int* in_sizes, int n_in,
                              void* d_out, int out_size, void* d_ws, size_t ws_size,
                              hipStream_t stream) {
    float* out = (float*)d_out;
    int* flag = (int*)d_ws;

    lfq_probe<<<1, 64, 0, stream>>>((const unsigned int*)d_in[0], flag);
    lfq_argmax_kernel<<<dim3(NT / TPB), dim3(512), 0, stream>>>(
        d_in[0], d_in[1], out, out_size, flag);
}

// Round 4
// 533.178 us; speedup vs baseline: 9.1616x; 9.1616x over previous
//
#include <hip/hip_runtime.h>
#include <hip/hip_bf16.h>

// LFQ argmax via split-bf16 MFMA: scores = x @ cb^T (fp32 inputs), argmax per
// token. fp32 = bf16_hi + bf16_lo; score ~= hi*hi + hi*lo + lo*hi (3 MFMAs,
// |err| <~ 1e-3 worst). Top-2 tracked per token; small-gap tokens rescored
// exactly in fp32 (round-3-validated dot). Output float32[16385].
#define NT 16384
#define ND 128
#define NC 16384
#define MARGIN 0.01f

typedef __bf16 bf16x8 __attribute__((ext_vector_type(8)));
typedef float f32x4 __attribute__((ext_vector_type(4)));

static __device__ __forceinline__ unsigned short f2bf(float f) {
    __hip_bfloat16 h = __float2bfloat16(f);   // RNE
    return *(unsigned short*)&h;
}
static __device__ __forceinline__ float bf2f(unsigned short u) {
    __hip_bfloat16 h = *(__hip_bfloat16*)&u;
    return __bfloat162float(h);
}

// ---------- hi/lo split conversion: x (2.1M fl) then cb (2.1M fl) ----------
__global__ __launch_bounds__(512) void lfq_convert(
    const float4* __restrict__ x4, const float4* __restrict__ cb4,
    ushort4* __restrict__ xh, ushort4* __restrict__ xl,
    ushort4* __restrict__ ch, ushort4* __restrict__ cl)
{
    const unsigned i = blockIdx.x * 512 + threadIdx.x;   // 0 .. 1048575
    const unsigned NX = NT * ND / 4;                     // 524288
    float4 v; ushort4* dh; ushort4* dl; unsigned j;
    if (i < NX) { v = x4[i];       dh = xh; dl = xl; j = i; }
    else        { v = cb4[i - NX]; dh = ch; dl = cl; j = i - NX; }

    ushort4 h, l;
    h.x = f2bf(v.x); l.x = f2bf(v.x - bf2f(h.x));
    h.y = f2bf(v.y); l.y = f2bf(v.y - bf2f(h.y));
    h.z = f2bf(v.z); l.z = f2bf(v.z - bf2f(h.z));
    h.w = f2bf(v.w); l.w = f2bf(v.w - bf2f(h.w));
    dh[j] = h; dl[j] = l;
}

// round-3-validated exact fp32 dot (same accumulator structure)
static __device__ __forceinline__ float exact_dot(
    const float4* __restrict__ xr4, const float* __restrict__ cf, int cidx)
{
    const float4* cr = (const float4*)(cf + (size_t)cidx * ND);
    float a0 = 0.f, a1 = 0.f, a2 = 0.f, a3 = 0.f;
#pragma unroll
    for (int i = 0; i < 32; i += 4) {
        float4 x0 = xr4[i+0], x1 = xr4[i+1], x2 = xr4[i+2], x3 = xr4[i+3];
        float4 c0 = cr[i+0],  c1 = cr[i+1],  c2 = cr[i+2],  c3 = cr[i+3];
        a0 += x0.x*c0.x + x0.y*c0.y + x0.z*c0.z + x0.w*c0.w;
        a1 += x1.x*c1.x + x1.y*c1.y + x1.z*c1.z + x1.w*c1.w;
        a2 += x2.x*c2.x + x2.y*c2.y + x2.z*c2.z + x2.w*c2.w;
        a3 += x3.x*c3.x + x3.y*c3.y + x3.z*c3.z + x3.w*c3.w;
    }
    return (a0 + a1) + (a2 + a3);
}

// ---------- main: 256 blocks x 512 thr; block = 64 tokens, full codebook ----
// wave w: token-group g=w>>2 (32 tokens), code-group q=w&3 (1/4 of code tiles)
__global__ __launch_bounds__(512, 2) void lfq_mfma_argmax(
    const unsigned short* __restrict__ xh, const unsigned short* __restrict__ xl,
    const unsigned short* __restrict__ ch, const unsigned short* __restrict__ cl,
    const float* __restrict__ xf, const float* __restrict__ cf,
    float* __restrict__ out, int out_size)
{
    const int tid  = threadIdx.x;
    const int w    = tid >> 6;
    const int lane = tid & 63;
    const int n    = lane & 15;
    const int quad = lane >> 4;
    const int g    = w >> 2;      // 0..1 token group
    const int q    = w & 3;       // 0..3 code group
    const int t0   = blockIdx.x * 64;

    // A fragments (hi+lo), 2 token-tiles x 4 k-chunks: A[m=n][k=quad*8+j]
    bf16x8 ah[2][4], al[2][4];
#pragma unroll
    for (int tt = 0; tt < 2; ++tt) {
        const size_t base = (size_t)(t0 + g * 32 + tt * 16 + n) * ND + quad * 8;
#pragma unroll
        for (int kk = 0; kk < 4; ++kk) {
            ah[tt][kk] = *(const bf16x8*)(xh + base + kk * 32);
            al[tt][kk] = *(const bf16x8*)(xl + base + kk * 32);
        }
    }

    float b1[2][4], b2[2][4];
    int   i1[2][4], i2[2][4];
#pragma unroll
    for (int tt = 0; tt < 2; ++tt)
#pragma unroll
        for (int r = 0; r < 4; ++r) {
            b1[tt][r] = -__builtin_inff(); i1[tt][r] = 0;
            b2[tt][r] = -__builtin_inff(); i2[tt][r] = 0;
        }

    // B stream: wave's tiles at codes q*16 + j*64, j=0..255; lane col = +n
    const size_t bbase = (size_t)(q * 16 + n) * ND + quad * 8;
    const unsigned short* pch = ch + bbase;
    const unsigned short* pcl = cl + bbase;

    bf16x8 Bh[2][4], Bl[2][4];
#pragma unroll
    for (int kk = 0; kk < 4; ++kk) {
        Bh[0][kk] = *(const bf16x8*)(pch + kk * 32);
        Bl[0][kk] = *(const bf16x8*)(pcl + kk * 32);
    }

#pragma unroll 2
    for (int j = 0; j < 256; ++j) {
        const int cur = j & 1, nxt = cur ^ 1;
        if (j < 255) {   // prefetch next tile (wave-uniform branch)
            const unsigned short* p1h = pch + (size_t)(j + 1) * (64 * ND);
            const unsigned short* p1l = pcl + (size_t)(j + 1) * (64 * ND);
#pragma unroll
            for (int kk = 0; kk < 4; ++kk) {
                Bh[nxt][kk] = *(const bf16x8*)(p1h + kk * 32);
                Bl[nxt][kk] = *(const bf16x8*)(p1l + kk * 32);
            }
        }
        const int code = q * 16 + j * 64 + n;
#pragma unroll
        for (int tt = 0; tt < 2; ++tt) {
            f32x4 acc = {0.f, 0.f, 0.f, 0.f};
#pragma unroll
            for (int kk = 0; kk < 4; ++kk) {
                acc = __builtin_amdgcn_mfma_f32_16x16x32_bf16(ah[tt][kk], Bh[cur][kk], acc, 0, 0, 0);
                acc = __builtin_amdgcn_mfma_f32_16x16x32_bf16(ah[tt][kk], Bl[cur][kk], acc, 0, 0, 0);
                acc = __builtin_amdgcn_mfma_f32_16x16x32_bf16(al[tt][kk], Bh[cur][kk], acc, 0, 0, 0);
            }
#pragma unroll
            for (int r = 0; r < 4; ++r) {
                const float v = acc[r];
                const bool c1 = v > b1[tt][r];
                const bool c2 = v > b2[tt][r];
                // new best2 = median(v, b1, b2); index follows the same cases
                i2[tt][r] = c1 ? i1[tt][r] : (c2 ? code : i2[tt][r]);
                b2[tt][r] = fminf(fmaxf(v, b2[tt][r]), b1[tt][r]);
                i1[tt][r] = c1 ? code : i1[tt][r];
                b1[tt][r] = fmaxf(v, b1[tt][r]);
            }
        }
    }

    // cross-lane top-2 merge over the 16 code-lanes per token row
#pragma unroll
    for (int tt = 0; tt < 2; ++tt)
#pragma unroll
        for (int r = 0; r < 4; ++r) {
#pragma unroll
            for (int off = 1; off < 16; off <<= 1) {
                float ob1 = __shfl_xor(b1[tt][r], off, 64);
                int   oi1 = __shfl_xor(i1[tt][r], off, 64);
                float ob2 = __shfl_xor(b2[tt][r], off, 64);
                int   oi2 = __shfl_xor(i2[tt][r], off, 64);
                bool gt = (ob1 > b1[tt][r]) ||
                          (ob1 == b1[tt][r] && oi1 < i1[tt][r]);
                float ls = gt ? b1[tt][r] : ob1;   // loser of the top-1 duel
                int   li = gt ? i1[tt][r] : oi1;
                float ws_ = gt ? ob2 : b2[tt][r];  // winner's runner-up
                int   wi = gt ? oi2 : i2[tt][r];
                bool s2 = (ls > ws_) || (ls == ws_ && li < wi);
                b2[tt][r] = s2 ? ls : ws_;
                i2[tt][r] = s2 ? li : wi;
                b1[tt][r] = gt ? ob1 : b1[tt][r];
                i1[tt][r] = gt ? oi1 : i1[tt][r];
            }
        }

    __shared__ float sb1[4][64], sb2[4][64];
    __shared__ int   si1[4][64], si2[4][64];
    if (n == 0) {
#pragma unroll
        for (int tt = 0; tt < 2; ++tt)
#pragma unroll
            for (int r = 0; r < 4; ++r) {
                const int tk = g * 32 + tt * 16 + quad * 4 + r;
                sb1[q][tk] = b1[tt][r]; si1[q][tk] = i1[tt][r];
                sb2[q][tk] = b2[tt][r]; si2[q][tk] = i2[tt][r];
            }
    }
    __syncthreads();

    if (tid < 64) {
        float B1 = sb1[0][tid], B2 = sb2[0][tid];
        int   I1 = si1[0][tid], I2 = si2[0][tid];
#pragma unroll
        for (int qq = 1; qq < 4; ++qq) {
            float ob1 = sb1[qq][tid], ob2 = sb2[qq][tid];
            int   oi1 = si1[qq][tid], oi2 = si2[qq][tid];
            bool gt = (ob1 > B1) || (ob1 == B1 && oi1 < I1);
            float ls = gt ? B1 : ob1;  int li = gt ? I1 : oi1;
            float ws_ = gt ? ob2 : B2; int wi = gt ? I2 : oi2;
            bool s2 = (ls > ws_) || (ls == ws_ && li < wi);
            B2 = s2 ? ls : ws_;  I2 = s2 ? li : wi;
            B1 = gt ? ob1 : B1;  I1 = gt ? oi1 : I1;
        }
        if (B1 - B2 <= MARGIN) {   // ambiguous under split error: exact rescore
            const float4* xr4 = (const float4*)(xf + (size_t)(t0 + tid) * ND);
            float s1 = exact_dot(xr4, cf, I1);
            float s2v = exact_dot(xr4, cf, I2);
            if (s2v > s1 || (s2v == s1 && I2 < I1)) I1 = I2;
        }
        out[t0 + tid] = (float)I1;
    }

    if (blockIdx.x == 0 && tid == 0 && out_size > NT)
        out[NT] = 0.0f;
}

// ---------- fallback: round-3 exact fp32 kernel (ws too small) ----------
__global__ __launch_bounds__(512) void lfq_fp32_argmax(
    const float* __restrict__ xf, const float* __restrict__ cf,
    float* __restrict__ out, int out_size)
{
    const int tid = threadIdx.x;
    const int w   = tid >> 6;
    const int tok = tid & 63;
    const int t0  = blockIdx.x * 64;
    __shared__ float s_sc[8][64];
    __shared__ int   s_ix[8][64];

    float4 xr[32];
    const float4* xrow = (const float4*)(xf + (size_t)(t0 + tok) * ND);
#pragma unroll
    for (int i = 0; i < 32; ++i) xr[i] = xrow[i];

    float bs = -__builtin_inff();
    int   bi = 0;
    const int c_begin = w * (NC / 8);
    for (int c = c_begin; c < c_begin + NC / 8; ++c) {
        const float4* crow = (const float4*)(cf + (size_t)c * ND);
        float a0 = 0.f, a1 = 0.f, a2 = 0.f, a3 = 0.f;
#pragma unroll
        for (int i = 0; i < 32; i += 4) {
            float4 v0 = crow[i+0], v1 = crow[i+1], v2 = crow[i+2], v3 = crow[i+3];
            a0 += xr[i+0].x*v0.x + xr[i+0].y*v0.y + xr[i+0].z*v0.z + xr[i+0].w*v0.w;
            a1 += xr[i+1].x*v1.x + xr[i+1].y*v1.y + xr[i+1].z*v1.z + xr[i+1].w*v1.w;
            a2 += xr[i+2].x*v2.x + xr[i+2].y*v2.y + xr[i+2].z*v2.z + xr[i+2].w*v2.w;
            a3 += xr[i+3].x*v3.x + xr[i+3].y*v3.y + xr[i+3].z*v3.z + xr[i+3].w*v3.w;
        }
        float s = (a0 + a1) + (a2 + a3);
        if (s > bs) { bs = s; bi = c; }
    }
    s_sc[w][tok] = bs; s_ix[w][tok] = bi;
    __syncthreads();
    if (tid < 64) {
        float bsf = s_sc[0][tid]; int bif = s_ix[0][tid];
#pragma unroll
        for (int ww = 1; ww < 8; ++ww) {
            float s2 = s_sc[ww][tid]; int i2 = s_ix[ww][tid];
            if (s2 > bsf || (s2 == bsf && i2 < bif)) { bsf = s2; bif = i2; }
        }
        out[t0 + tid] = (float)bif;
    }
    if (blockIdx.x == 0 && tid == 0 && out_size > NT) out[NT] = 0.0f;
}

extern "C" void kernel_launch(void* const* d_in, const int* in_sizes, int n_in,
                              void* d_out, int out_size, void* d_ws, size_t ws_size,
                              hipStream_t stream) {
    const float* x  = (const float*)d_in[0];
    const float* cb = (const float*)d_in[1];
    float* out = (float*)d_out;

    const size_t ARR = (size_t)NT * ND;         // 2,097,152 elements (4 MB each)
    if (ws_size >= 4 * ARR * sizeof(unsigned short)) {
        unsigned short* ws = (unsigned short*)d_ws;
        unsigned short *xh = ws, *xl = ws + ARR, *ch = ws + 2 * ARR, *cl = ws + 3 * ARR;
        lfq_convert<<<dim3(2048), dim3(512), 0, stream>>>(
            (const float4*)x, (const float4*)cb,
            (ushort4*)xh, (ushort4*)xl, (ushort4*)ch, (ushort4*)cl);
        lfq_mfma_argmax<<<dim3(NT / 64), dim3(512), 0, stream>>>(
            xh, xl, ch, cl, x, cb, out, out_size);
    } else {
        lfq_fp32_argmax<<<dim3(NT / 64), dim3(512), 0, stream>>>(x, cb, out, out_size);
    }
}